// Round 7
// baseline (192.507 us; speedup 1.0000x reference)
//
#include <hip/hip_runtime.h>

#define HW 64
#define CIN 256
#define OC1 128
#define NJ 49
#define KZ 8                 // K-split: each conv1 block does 32 ic x 49 taps

typedef short bf16x8 __attribute__((ext_vector_type(8)));
typedef float f32x4 __attribute__((ext_vector_type(4)));

__device__ __forceinline__ unsigned f2bf_pack(float a, float b) {
    unsigned ua = __float_as_uint(a);
    ua += 0x7FFF + ((ua >> 16) & 1);
    unsigned ub = __float_as_uint(b);
    ub += 0x7FFF + ((ub >> 16) & 1);
    return (ua >> 16) | (ub & 0xFFFF0000u);
}

__device__ __forceinline__ unsigned short f2bf(float a) {
    unsigned u = __float_as_uint(a);
    u += 0x7FFF + ((u >> 16) & 1);
    return (unsigned short)(u >> 16);
}

// ---------------------------------------------------------------------------
// w1 fp32 [128 oc][256 ic][49 tap] -> w1t bf16 [kz 8][tap 49][oc 128][ic 32]
// ---------------------------------------------------------------------------
__global__ __launch_bounds__(256) void wtrans_kernel(const float* __restrict__ w1,
                                                     unsigned short* __restrict__ w1t) {
    __shared__ float ws[128 * 49];    // [ic-local 128][tap 49]
    const int oc = blockIdx.x >> 1, ih = blockIdx.x & 1;
    const float4* src = (const float4*)(w1 + ((size_t)oc * 256 + ih * 128) * 49);
    for (int f = threadIdx.x; f < 1568; f += 256)
        ((float4*)ws)[f] = src[f];
    __syncthreads();
    for (int f = threadIdx.x; f < 4 * 49 * 32; f += 256) {
        const int icl = f & 31, r = f >> 5;          // r = kzl*49 + tap
        const int kzl = r / 49, tap = r - kzl * 49;
        // LDS read stride 49 words (odd) -> conflict-free
        w1t[(((size_t)(ih * 4 + kzl) * 49 + tap) * 128 + oc) * 32 + icl] =
            f2bf(ws[(kzl * 32 + icl) * 49 + tap]);
    }
}

// ---------------------------------------------------------------------------
// x fp32 [b][256 c][64 h][64 w] -> xbf bf16 [b][76 pr][80 col][256 ic]
// pr = h + 6, col = w + 8; pad regions zeroed.
// float4 reads, 4x4 microtile transpose via XOR-swizzled uint2 LDS.
// grid (76 pr, 4 b, 2 ic-half), block 256.
// ---------------------------------------------------------------------------
__global__ __launch_bounds__(256) void xtrans_kernel(const float* __restrict__ x,
                                                     unsigned short* __restrict__ xbf) {
    __shared__ uint2 lsq[64 * 32];   // [w][c4], c4 XOR-swizzled by (w&31)
    const int pr = blockIdx.x, b = blockIdx.y, ih = blockIdx.z;
    const int t = threadIdx.x;
    const int h = pr - 6;
    unsigned short* obrow = xbf + ((size_t)b * 76 + pr) * 80 * 256;

    if ((unsigned)h >= 64u) {      // top/bottom pad rows: zero our ic-half
        const uint4 z = make_uint4(0, 0, 0, 0);
        for (int f = t; f < 80 * 16; f += 256) {
            const int col = f >> 4, k = f & 15;      // 16 uint4 per 128 shorts
            ((uint4*)obrow)[col * 32 + ih * 16 + k] = z;
        }
        return;
    }
    const float4* xr4 = (const float4*)(x + ((size_t)b * CIN + ih * 128) * 4096
                                        + (size_t)h * 64);
    #pragma unroll
    for (int i = 0; i < 2; ++i) {
        const int mt = t + i * 256;          // 512 microtiles: (w4 16) x (c4 32)
        const int w4 = mt & 15, c4 = mt >> 4;
        const float4 r0 = xr4[(size_t)(c4 * 4 + 0) * 1024 + w4];
        const float4 r1 = xr4[(size_t)(c4 * 4 + 1) * 1024 + w4];
        const float4 r2 = xr4[(size_t)(c4 * 4 + 2) * 1024 + w4];
        const float4 r3 = xr4[(size_t)(c4 * 4 + 3) * 1024 + w4];
        const float a0[4] = {r0.x, r0.y, r0.z, r0.w};
        const float a1[4] = {r1.x, r1.y, r1.z, r1.w};
        const float a2[4] = {r2.x, r2.y, r2.z, r2.w};
        const float a3[4] = {r3.x, r3.y, r3.z, r3.w};
        #pragma unroll
        for (int j = 0; j < 4; ++j) {
            const int w = w4 * 4 + j;
            lsq[w * 32 + (c4 ^ (w & 31))] =
                make_uint2(f2bf_pack(a0[j], a1[j]), f2bf_pack(a2[j], a3[j]));
        }
    }
    __syncthreads();
    uint2* oq = (uint2*)obrow;
    #pragma unroll
    for (int k = 0; k < 10; ++k) {           // 80 cols x 32 c4 / 256 threads
        const int f = t + k * 256;
        const int col = f >> 5, c4 = f & 31;
        const int w = col - 8;
        uint2 v = make_uint2(0, 0);
        if ((unsigned)w < 64u) v = lsq[w * 32 + (c4 ^ (w & 31))];
        oq[col * 64 + ih * 32 + c4] = v;
    }
}

// ---------------------------------------------------------------------------
// conv1 implicit GEMM, bf16 MFMA 16x16x32, KZ=8.
// grid (32 hp, 8 kz, 4 b) = 1024 blocks; block 128 = 2 waves.
// Wave = 64oc x 128px (2 rows x 64w): acc[4][8] (128 regs), 32 MFMA/tap from
// 4 global wf + 8 LDS xf reads. Big register tile cuts LDS-read pipe time
// from 47us/CU (round 6, the measured bottleneck) to ~16us/CU -- below the
// 21us MFMA floor. Weights read straight from L2-resident w1t (620 cyc of
// indep MFMA per tap covers the ~200cy L2 latency); no wbuf -> LDS 20,480 B
// -> 8 blocks/CU -> 4 waves/SIMD TLP on top of the in-wave ILP.
// ---------------------------------------------------------------------------
__global__ __launch_bounds__(128) void conv1_mfma_kernel(
    const unsigned short* __restrict__ xbf, const unsigned short* __restrict__ w1t,
    unsigned short* __restrict__ P)
{
    __shared__ unsigned short xs[2][5120];   // 2 x 10,240 B: [row 2][col 80][ic32]

    const int hp = blockIdx.x, kz = blockIdx.y, b = blockIdx.z;
    const int h0 = hp * 2;
    const int t = threadIdx.x;               // 0..127
    const int lane = t & 63, wv = t >> 6;    // 2 waves
    const int oc_off = wv * 64;
    const int l15 = lane & 15, quad = lane >> 4;

    f32x4 acc[4][8];                         // [oc-frag][px-frag]
    #pragma unroll
    for (int i = 0; i < 4; ++i)
        #pragma unroll
        for (int j = 0; j < 8; ++j) acc[i][j] = (f32x4){0.f, 0.f, 0.f, 0.f};

    const unsigned short* wbase =
        w1t + ((size_t)kz * 49 * 128 + oc_off + l15) * 32 + quad * 8;
    const unsigned short* xrow =
        xbf + ((size_t)b * 76 + h0) * 80 * 256 + kz * 32;   // pr = h0 base

    // X tile: 640 16B chunks; chunk L: cell=L>>2 (row*80+col), qc=L&3.
    // source quad pre-swizzled: qs = qc ^ ((col>>1)&3); LDS dest linear.
    // 128 threads -> 5 chunks/thread, no mask.
#define STAGE_X(u_, bs_) do {                                                  \
    unsigned short* lb_ = &xs[bs_][0];                                         \
    _Pragma("unroll")                                                          \
    for (int i_ = 0; i_ < 5; ++i_) {                                           \
        const int L_ = i_ * 128 + t;                                           \
        const int cell_ = L_ >> 2, qc_ = L_ & 3;                               \
        const int row_ = (cell_ >= 80) ? 1 : 0;                               \
        const int col_ = cell_ - row_ * 80;                                   \
        const int qs_ = qc_ ^ ((col_ >> 1) & 3);                               \
        const unsigned short* src_ =                                           \
            xrow + ((size_t)(2 * (u_) + row_) * 80 + col_) * 256 + qs_ * 8;    \
        __builtin_amdgcn_global_load_lds(                                      \
            (const __attribute__((address_space(1))) unsigned int*)src_,       \
            (__attribute__((address_space(3))) unsigned int*)                  \
                (lb_ + ((size_t)i_ * 128 + (t & ~63)) * 8),                    \
            16, 0, 0);                                                         \
    }                                                                          \
} while (0)

    STAGE_X(0, 0);
    __syncthreads();

    #pragma unroll 1
    for (int u = 0; u < 7; ++u) {
        if (u < 6) STAGE_X(u + 1, (u + 1) & 1);   // drained by section barrier
        const char* cb = (const char*)&xs[u & 1][0];
        const unsigned short* wu = wbase + (size_t)u * 7 * 4096;
        #pragma unroll
        for (int v = 0; v < 7; ++v) {
            const unsigned short* wp = wu + (size_t)v * 4096;
            bf16x8 wf0 = *(const bf16x8*)(wp);          // 1KB coalesced L2 hits
            bf16x8 wf1 = *(const bf16x8*)(wp + 512);
            bf16x8 wf2 = *(const bf16x8*)(wp + 1024);
            bf16x8 wf3 = *(const bf16x8*)(wp + 1536);
            #pragma unroll
            for (int pf = 0; pf < 8; ++pf) {
                const int ri_ = pf >> 2;                 // px row
                const int c = (pf & 3) * 16 + l15 + 2 * v + 2;
                const int sw = (quad ^ ((c >> 1) & 3)) << 4;
                bf16x8 xf = *(const bf16x8*)(cb + (ri_ * 80 + c) * 64 + sw);
                acc[0][pf] = __builtin_amdgcn_mfma_f32_16x16x32_bf16(wf0, xf, acc[0][pf], 0,0,0);
                acc[1][pf] = __builtin_amdgcn_mfma_f32_16x16x32_bf16(wf1, xf, acc[1][pf], 0,0,0);
                acc[2][pf] = __builtin_amdgcn_mfma_f32_16x16x32_bf16(wf2, xf, acc[2][pf], 0,0,0);
                acc[3][pf] = __builtin_amdgcn_mfma_f32_16x16x32_bf16(wf3, xf, acc[3][pf], 0,0,0);
            }
        }
        __syncthreads();
    }
#undef STAGE_X

    unsigned short* Pb = P + (size_t)(kz * 4 + b) * (128 * 4096) + (size_t)h0 * 64;
    #pragma unroll
    for (int of = 0; of < 4; ++of) {
        const int oc = oc_off + of * 16 + quad * 4;
        #pragma unroll
        for (int pf = 0; pf < 8; ++pf) {
            const int row = pf >> 2;
            const int w = (pf & 3) * 16 + l15;
            #pragma unroll
            for (int reg = 0; reg < 4; ++reg)
                Pb[(size_t)(oc + reg) * 4096 + row * 64 + w] = f2bf(acc[of][pf][reg]);
        }
    }
}

// ---------------------------------------------------------------------------
// attn: conv2 (1x1, 128->49) + b2 + softmax -> A[b][49][h][w] f32 (global).
// grid (64 h, 4 b) = 256 blocks; block 512. (= old conv2 phases A+B+softmax)
// ---------------------------------------------------------------------------
__global__ __launch_bounds__(512, 2) void attn_kernel(
    const unsigned short* __restrict__ P, const float* __restrict__ w2,
    const float* __restrict__ b2, const float* __restrict__ b1,
    float* __restrict__ A)
{
    __shared__ float k1s[64 * 140];   // 35,840 B
    __shared__ float k2s[64 * 56];    // 14,336 B
    const int h = blockIdx.x, b = blockIdx.y;
    const int t = threadIdx.x;

    for (int f = t; f < OC1 * 64; f += 512) {
        int w = f & 63, oc = f >> 6;
        float s = b1[oc];
        #pragma unroll
        for (int kzi = 0; kzi < KZ; ++kzi) {
            unsigned u = P[(((size_t)(kzi * 4 + b) * 128 + oc) * 64 + h) * 64 + w];
            s += __uint_as_float(u << 16);
        }
        k1s[w * 140 + oc] = s;
    }
    __syncthreads();

    const int w = t & 63, jg = t >> 6;
    float accj[7];
    if (jg < 7) {
        #pragma unroll
        for (int jj = 0; jj < 7; ++jj) accj[jj] = b2[7 * jg + jj];
        const float4* kv = (const float4*)&k1s[w * 140];
        for (int oc4 = 0; oc4 < 32; ++oc4) {
            float4 v = kv[oc4];
            #pragma unroll
            for (int jj = 0; jj < 7; ++jj) {
                const float* wr = w2 + (size_t)(7 * jg + jj) * OC1 + 4 * oc4;
                accj[jj] += v.x * wr[0] + v.y * wr[1] + v.z * wr[2] + v.w * wr[3];
            }
        }
        #pragma unroll
        for (int jj = 0; jj < 7; ++jj) k2s[w * 56 + 7 * jg + jj] = accj[jj];
    } else {
        #pragma unroll
        for (int j = 49; j < 56; ++j) k2s[w * 56 + j] = -1e30f;
    }
    __syncthreads();

    float4 vv[13];
    const float4* k2v = (const float4*)&k2s[w * 56];
    float m = -1e30f;
    #pragma unroll
    for (int i = 0; i < 13; ++i) {
        vv[i] = k2v[i];
        m = fmaxf(m, fmaxf(fmaxf(vv[i].x, vv[i].y), fmaxf(vv[i].z, vv[i].w)));
    }
    float s = 0.f;
    #pragma unroll
    for (int i = 0; i < 13; ++i) {
        s += __expf(vv[i].x - m) + __expf(vv[i].y - m)
           + __expf(vv[i].z - m) + __expf(vv[i].w - m);
    }
    const float inv = 1.f / s;
    if (jg < 7) {
        #pragma unroll
        for (int jj = 0; jj < 7; ++jj)
            A[((size_t)b * NJ + 7 * jg + jj) * 4096 + h * 64 + w] =
                __expf(accj[jj] - m) * inv;
    }
}

// ---------------------------------------------------------------------------
// gather: 49-tap dilated softmax-weighted sum, one 64-channel pass per block.
// grid (64 h, 4 b, 4 pass) = 1024 blocks; block 512; LDS 12.5 KB -> high TLP.
// ---------------------------------------------------------------------------
__global__ __launch_bounds__(512) void gather_kernel(
    const float* __restrict__ A, const float* __restrict__ x,
    float* __restrict__ out)
{
    __shared__ float as[NJ * 64];     // 12,544 B
    const int h = blockIdx.x, b = blockIdx.y, pass = blockIdx.z;
    const int t = threadIdx.x;

    for (int f = t; f < NJ * 64; f += 512)
        as[f] = A[((size_t)b * NJ + (f >> 6)) * 4096 + h * 64 + (f & 63)];
    __syncthreads();

    // thread = (wp 16) x (cs 32); this block covers channels pass*64..+63.
    const int wp = t & 15, cs = t >> 4;
    const int w0 = wp * 4;
    float* outb = out + (size_t)b * CIN * 4096 + (size_t)h * 64 + w0;

    const int c0 = pass * 64 + cs * 2;
    const float* xb = x + (size_t)(b * CIN + c0) * 4096;
    float ac[2][4];
    #pragma unroll
    for (int c = 0; c < 2; ++c)
        #pragma unroll
        for (int wi = 0; wi < 4; ++wi) ac[c][wi] = 0.f;

    #pragma unroll
    for (int u = 0; u < 7; ++u) {
        const int row = h + 2 * u - 6;
        if ((unsigned)row >= 64u) continue;
        float xr[2][20];
        #pragma unroll
        for (int c = 0; c < 2; ++c) {
            const float4* rp = (const float4*)(xb + (size_t)c * 4096 + row * 64);
            #pragma unroll
            for (int j = 0; j < 5; ++j) {
                const int i4 = wp - 2 + j;
                float4 g = make_float4(0.f, 0.f, 0.f, 0.f);
                if ((unsigned)i4 < 16u) g = rp[i4];
                xr[c][4 * j + 0] = g.x; xr[c][4 * j + 1] = g.y;
                xr[c][4 * j + 2] = g.z; xr[c][4 * j + 3] = g.w;
            }
        }
        #pragma unroll
        for (int v = 0; v < 7; ++v) {
            const float4 a4 = *(const float4*)&as[(u * 7 + v) * 64 + w0];
            const float av[4] = {a4.x, a4.y, a4.z, a4.w};
            #pragma unroll
            for (int wi = 0; wi < 4; ++wi)
                #pragma unroll
                for (int c = 0; c < 2; ++c)
                    ac[c][wi] += av[wi] * xr[c][wi + 2 * v + 2];
        }
    }
    #pragma unroll
    for (int c = 0; c < 2; ++c) {
        float4 st = make_float4(ac[c][0], ac[c][1], ac[c][2], ac[c][3]);
        *(float4*)&outb[(size_t)(c0 + c) * 4096] = st;
    }
}

// ---------------------------------------------------------------------------
// ws layout:
//   w1t bf16 [8][49][128][32]            3,211,264 B   (dead after conv1)
//   A   f32  [4][49][64][64]             3,211,264 B   -- ALIASED onto w1t
//   xbf bf16 [4][76][80][256]           12,451,840 B
//   P   bf16 [8][4][128][4096]          33,554,432 B   (total ~49.2 MB)
// ---------------------------------------------------------------------------
extern "C" void kernel_launch(void* const* d_in, const int* in_sizes, int n_in,
                              void* d_out, int out_size, void* d_ws, size_t ws_size,
                              hipStream_t stream) {
    const float* x  = (const float*)d_in[0];
    const float* w1 = (const float*)d_in[1];
    const float* b1 = (const float*)d_in[2];
    const float* w2 = (const float*)d_in[3];
    const float* b2 = (const float*)d_in[4];
    float* out = (float*)d_out;

    unsigned short* w1t = (unsigned short*)d_ws;
    float*          Abuf = (float*)d_ws;                 // alias: w1t dead by then
    unsigned short* xbf = (unsigned short*)((char*)d_ws + 3211264);
    unsigned short* P   = (unsigned short*)((char*)d_ws + 3211264 + 12451840);

    wtrans_kernel<<<256, 256, 0, stream>>>(w1, w1t);
    xtrans_kernel<<<dim3(76, 4, 2), 256, 0, stream>>>(x, xbf);
    conv1_mfma_kernel<<<dim3(32, KZ, 4), 128, 0, stream>>>(xbf, w1t, P);
    attn_kernel<<<dim3(HW, 4), 512, 0, stream>>>(P, w2, b2, b1, Abuf);
    gather_kernel<<<dim3(HW, 4, 4), 512, 0, stream>>>(Abuf, x, out);
}

// Round 8
// 176.706 us; speedup vs baseline: 1.0894x; 1.0894x over previous
//
#include <hip/hip_runtime.h>

#define HW 64
#define CIN 256
#define OC1 128
#define NJ 49
#define KZ 8                 // K-split: each conv1 block does 32 ic x 49 taps

typedef short bf16x8 __attribute__((ext_vector_type(8)));
typedef float f32x4 __attribute__((ext_vector_type(4)));

__device__ __forceinline__ unsigned f2bf_pack(float a, float b) {
    unsigned ua = __float_as_uint(a);
    ua += 0x7FFF + ((ua >> 16) & 1);
    unsigned ub = __float_as_uint(b);
    ub += 0x7FFF + ((ub >> 16) & 1);
    return (ua >> 16) | (ub & 0xFFFF0000u);
}

__device__ __forceinline__ unsigned short f2bf(float a) {
    unsigned u = __float_as_uint(a);
    u += 0x7FFF + ((u >> 16) & 1);
    return (unsigned short)(u >> 16);
}

// ---------------------------------------------------------------------------
// w1 fp32 [128 oc][256 ic][49 tap] -> w1t bf16 [kz 8][tap 49][oc 128][ic 32]
// ---------------------------------------------------------------------------
__global__ __launch_bounds__(256) void wtrans_kernel(const float* __restrict__ w1,
                                                     unsigned short* __restrict__ w1t) {
    __shared__ float ws[128 * 49];    // [ic-local 128][tap 49]
    const int oc = blockIdx.x >> 1, ih = blockIdx.x & 1;
    const float4* src = (const float4*)(w1 + ((size_t)oc * 256 + ih * 128) * 49);
    for (int f = threadIdx.x; f < 1568; f += 256)
        ((float4*)ws)[f] = src[f];
    __syncthreads();
    for (int f = threadIdx.x; f < 4 * 49 * 32; f += 256) {
        const int icl = f & 31, r = f >> 5;          // r = kzl*49 + tap
        const int kzl = r / 49, tap = r - kzl * 49;
        // LDS read stride 49 words (odd) -> conflict-free
        w1t[(((size_t)(ih * 4 + kzl) * 49 + tap) * 128 + oc) * 32 + icl] =
            f2bf(ws[(kzl * 32 + icl) * 49 + tap]);
    }
}

// ---------------------------------------------------------------------------
// x fp32 [b][256 c][64 h][64 w] -> xbf bf16 [b][76 pr][80 col][256 ic]
// pr = h + 6, col = w + 8; pad regions zeroed.
// float4 reads, 4x4 microtile transpose via XOR-swizzled uint2 LDS.
// grid (76 pr, 4 b, 2 ic-half), block 256.
// ---------------------------------------------------------------------------
__global__ __launch_bounds__(256) void xtrans_kernel(const float* __restrict__ x,
                                                     unsigned short* __restrict__ xbf) {
    __shared__ uint2 lsq[64 * 32];   // [w][c4], c4 XOR-swizzled by (w&31)
    const int pr = blockIdx.x, b = blockIdx.y, ih = blockIdx.z;
    const int t = threadIdx.x;
    const int h = pr - 6;
    unsigned short* obrow = xbf + ((size_t)b * 76 + pr) * 80 * 256;

    if ((unsigned)h >= 64u) {      // top/bottom pad rows: zero our ic-half
        const uint4 z = make_uint4(0, 0, 0, 0);
        for (int f = t; f < 80 * 16; f += 256) {
            const int col = f >> 4, k = f & 15;      // 16 uint4 per 128 shorts
            ((uint4*)obrow)[col * 32 + ih * 16 + k] = z;
        }
        return;
    }
    const float4* xr4 = (const float4*)(x + ((size_t)b * CIN + ih * 128) * 4096
                                        + (size_t)h * 64);
    #pragma unroll
    for (int i = 0; i < 2; ++i) {
        const int mt = t + i * 256;          // 512 microtiles: (w4 16) x (c4 32)
        const int w4 = mt & 15, c4 = mt >> 4;
        const float4 r0 = xr4[(size_t)(c4 * 4 + 0) * 1024 + w4];
        const float4 r1 = xr4[(size_t)(c4 * 4 + 1) * 1024 + w4];
        const float4 r2 = xr4[(size_t)(c4 * 4 + 2) * 1024 + w4];
        const float4 r3 = xr4[(size_t)(c4 * 4 + 3) * 1024 + w4];
        const float a0[4] = {r0.x, r0.y, r0.z, r0.w};
        const float a1[4] = {r1.x, r1.y, r1.z, r1.w};
        const float a2[4] = {r2.x, r2.y, r2.z, r2.w};
        const float a3[4] = {r3.x, r3.y, r3.z, r3.w};
        #pragma unroll
        for (int j = 0; j < 4; ++j) {
            const int w = w4 * 4 + j;
            lsq[w * 32 + (c4 ^ (w & 31))] =
                make_uint2(f2bf_pack(a0[j], a1[j]), f2bf_pack(a2[j], a3[j]));
        }
    }
    __syncthreads();
    uint2* oq = (uint2*)obrow;
    #pragma unroll
    for (int k = 0; k < 10; ++k) {           // 80 cols x 32 c4 / 256 threads
        const int f = t + k * 256;
        const int col = f >> 5, c4 = f & 31;
        const int w = col - 8;
        uint2 v = make_uint2(0, 0);
        if ((unsigned)w < 64u) v = lsq[w * 32 + (c4 ^ (w & 31))];
        oq[col * 64 + ih * 32 + c4] = v;
    }
}

// ---------------------------------------------------------------------------
// conv1 implicit GEMM, bf16 MFMA 16x16x32, KZ=8.
// grid (32 hp, 8 kz, 4 b) = 1024 blocks; block 256 = 4 waves.
// Wave = 64oc x 64px (round-5 proven tile: acc[4][4] = 64 AGPR) + round-6's
// W-in-LDS (7-tap section, 56KB, quad-XOR swizzle). Per wave-tap: 4 wf + 4 xf
// ds_read_b128 + 16 MFMA -> per-CU LDS read traffic 6.3 MB (~31us) vs round
// 6's 9.6 MB (~47us, the measured bottleneck); MFMA floor 25us. Regs ~119
// total (no spill, no cliff). LDS 77,824 -> 2 blocks/CU co-resident.
// ---------------------------------------------------------------------------
__global__ __launch_bounds__(256) void conv1_mfma_kernel(
    const unsigned short* __restrict__ xbf, const unsigned short* __restrict__ w1t,
    unsigned short* __restrict__ P)
{
    __shared__ unsigned short wbuf[7 * 128 * 32];   // 57,344 B: [tap][oc][ic32] swz
    __shared__ unsigned short xs[2][5120];          // 20,480 B: [row 2][col 80][ic32]

    const int hp = blockIdx.x, kz = blockIdx.y, b = blockIdx.z;
    const int h0 = hp * 2;
    const int t = threadIdx.x;               // 0..255
    const int lane = t & 63, wv = t >> 6;    // 4 waves
    const int oc_off = (wv & 1) * 64;
    const int ri = wv >> 1;                  // wave-uniform pixel row (0/1)
    const int l15 = lane & 15, quad = lane >> 4;
    const int wvbase = t & ~63;
    // quad-XOR swizzle term for wf reads ((oc_off+of*16)>>1 & 3 == 0)
    const int swf = (quad ^ ((l15 >> 1) & 3)) << 4;

    f32x4 acc[4][4];
    #pragma unroll
    for (int i = 0; i < 4; ++i)
        #pragma unroll
        for (int j = 0; j < 4; ++j) acc[i][j] = (f32x4){0.f, 0.f, 0.f, 0.f};

    const unsigned short* xrow =
        xbf + ((size_t)b * 76 + h0) * 80 * 256 + kz * 32;   // pr = h0 base

    // X tile: 640 16B chunks; chunk L: cell=L>>2 (row*80+col), qc=L&3.
    // source quad pre-swizzled: qs = qc ^ ((col>>1)&3); LDS dest linear.
#define STAGE_X(u_, bs_) do {                                                  \
    unsigned short* lb_ = &xs[bs_][0];                                         \
    _Pragma("unroll")                                                          \
    for (int i_ = 0; i_ < 3; ++i_) {                                           \
        if (i_ < 2 || t < 128) {        /* wave-uniform mask */                \
            const int L_ = i_ * 256 + t;                                       \
            const int cell_ = L_ >> 2, qc_ = L_ & 3;                           \
            const int row_ = (cell_ >= 80) ? 1 : 0;                           \
            const int col_ = cell_ - row_ * 80;                               \
            const int qs_ = qc_ ^ ((col_ >> 1) & 3);                           \
            const unsigned short* src_ =                                       \
                xrow + ((size_t)(2 * (u_) + row_) * 80 + col_) * 256 + qs_ * 8;\
            __builtin_amdgcn_global_load_lds(                                  \
                (const __attribute__((address_space(1))) unsigned int*)src_,   \
                (__attribute__((address_space(3))) unsigned int*)              \
                    (lb_ + ((size_t)i_ * 256 + wvbase) * 8),                   \
                16, 0, 0);                                                     \
        }                                                                      \
    }                                                                          \
} while (0)

    // W section: 3584 16B chunks (7 taps x 128 oc x 4 quads); 14 per thread.
    // chunk c: tap=c>>9, oc=(c>>2)&127, qc=c&3; source quad pre-swizzled.
#define STAGE_W(u_) do {                                                       \
    const unsigned short* wsu_ = w1t + ((size_t)kz * 49 + (u_) * 7) * 4096;    \
    _Pragma("unroll")                                                          \
    for (int i_ = 0; i_ < 14; ++i_) {                                          \
        const int c_ = t + i_ * 256;                                           \
        const int tap_ = c_ >> 9, r_ = c_ & 511;                               \
        const int oc_ = r_ >> 2, qc_ = r_ & 3;                                 \
        const int qs_ = qc_ ^ ((oc_ >> 1) & 3);                                \
        const unsigned short* src_ =                                           \
            wsu_ + ((size_t)tap_ * 128 + oc_) * 32 + qs_ * 8;                  \
        __builtin_amdgcn_global_load_lds(                                      \
            (const __attribute__((address_space(1))) unsigned int*)src_,       \
            (__attribute__((address_space(3))) unsigned int*)                  \
                ((unsigned short*)wbuf + ((size_t)i_ * 256 + wvbase) * 8),     \
            16, 0, 0);                                                         \
    }                                                                          \
} while (0)

    STAGE_W(0);
    STAGE_X(0, 0);
    __syncthreads();

    #pragma unroll 1
    for (int u = 0; u < 7; ++u) {
        if (u < 6) STAGE_X(u + 1, (u + 1) & 1);   // drained by section barrier
        const char* cb = (const char*)&xs[u & 1][0];
        #pragma unroll
        for (int v = 0; v < 7; ++v) {
            const char* wt = (const char*)wbuf + v * 8192;
            bf16x8 wf0 = *(const bf16x8*)(wt + (oc_off      + l15) * 64 + swf);
            bf16x8 wf1 = *(const bf16x8*)(wt + (oc_off + 16 + l15) * 64 + swf);
            bf16x8 wf2 = *(const bf16x8*)(wt + (oc_off + 32 + l15) * 64 + swf);
            bf16x8 wf3 = *(const bf16x8*)(wt + (oc_off + 48 + l15) * 64 + swf);
            const int sc = l15 + 2 * v + 2;
            const int sw = (quad ^ ((sc >> 1) & 3)) << 4;  // same for all pf
            bf16x8 xf0 = *(const bf16x8*)(cb + (ri * 80 + sc     ) * 64 + sw);
            bf16x8 xf1 = *(const bf16x8*)(cb + (ri * 80 + sc + 16) * 64 + sw);
            bf16x8 xf2 = *(const bf16x8*)(cb + (ri * 80 + sc + 32) * 64 + sw);
            bf16x8 xf3 = *(const bf16x8*)(cb + (ri * 80 + sc + 48) * 64 + sw);
            acc[0][0] = __builtin_amdgcn_mfma_f32_16x16x32_bf16(wf0, xf0, acc[0][0], 0,0,0);
            acc[0][1] = __builtin_amdgcn_mfma_f32_16x16x32_bf16(wf0, xf1, acc[0][1], 0,0,0);
            acc[0][2] = __builtin_amdgcn_mfma_f32_16x16x32_bf16(wf0, xf2, acc[0][2], 0,0,0);
            acc[0][3] = __builtin_amdgcn_mfma_f32_16x16x32_bf16(wf0, xf3, acc[0][3], 0,0,0);
            acc[1][0] = __builtin_amdgcn_mfma_f32_16x16x32_bf16(wf1, xf0, acc[1][0], 0,0,0);
            acc[1][1] = __builtin_amdgcn_mfma_f32_16x16x32_bf16(wf1, xf1, acc[1][1], 0,0,0);
            acc[1][2] = __builtin_amdgcn_mfma_f32_16x16x32_bf16(wf1, xf2, acc[1][2], 0,0,0);
            acc[1][3] = __builtin_amdgcn_mfma_f32_16x16x32_bf16(wf1, xf3, acc[1][3], 0,0,0);
            acc[2][0] = __builtin_amdgcn_mfma_f32_16x16x32_bf16(wf2, xf0, acc[2][0], 0,0,0);
            acc[2][1] = __builtin_amdgcn_mfma_f32_16x16x32_bf16(wf2, xf1, acc[2][1], 0,0,0);
            acc[2][2] = __builtin_amdgcn_mfma_f32_16x16x32_bf16(wf2, xf2, acc[2][2], 0,0,0);
            acc[2][3] = __builtin_amdgcn_mfma_f32_16x16x32_bf16(wf2, xf3, acc[2][3], 0,0,0);
            acc[3][0] = __builtin_amdgcn_mfma_f32_16x16x32_bf16(wf3, xf0, acc[3][0], 0,0,0);
            acc[3][1] = __builtin_amdgcn_mfma_f32_16x16x32_bf16(wf3, xf1, acc[3][1], 0,0,0);
            acc[3][2] = __builtin_amdgcn_mfma_f32_16x16x32_bf16(wf3, xf2, acc[3][2], 0,0,0);
            acc[3][3] = __builtin_amdgcn_mfma_f32_16x16x32_bf16(wf3, xf3, acc[3][3], 0,0,0);
        }
        __syncthreads();                  // tap reads done; X(u+1) drained
        if (u < 6) {
            STAGE_W(u + 1);               // wbuf free now; drain covered by
            __syncthreads();              // co-resident block
        }
    }
#undef STAGE_X
#undef STAGE_W

    unsigned short* Pb = P + (size_t)(kz * 4 + b) * (128 * 4096) + (size_t)(h0 + ri) * 64;
    #pragma unroll
    for (int of = 0; of < 4; ++of) {
        const int oc = oc_off + of * 16 + quad * 4;
        #pragma unroll
        for (int pf = 0; pf < 4; ++pf) {
            const int w = pf * 16 + l15;
            #pragma unroll
            for (int reg = 0; reg < 4; ++reg)
                Pb[(size_t)(oc + reg) * 4096 + w] = f2bf(acc[of][pf][reg]);
        }
    }
}

// ---------------------------------------------------------------------------
// attn: conv2 (1x1, 128->49) + b2 + softmax -> A[b][49][h][w] f32 (global).
// grid (64 h, 4 b) = 256 blocks; block 512. (= old conv2 phases A+B+softmax)
// ---------------------------------------------------------------------------
__global__ __launch_bounds__(512, 2) void attn_kernel(
    const unsigned short* __restrict__ P, const float* __restrict__ w2,
    const float* __restrict__ b2, const float* __restrict__ b1,
    float* __restrict__ A)
{
    __shared__ float k1s[64 * 140];   // 35,840 B
    __shared__ float k2s[64 * 56];    // 14,336 B
    const int h = blockIdx.x, b = blockIdx.y;
    const int t = threadIdx.x;

    for (int f = t; f < OC1 * 64; f += 512) {
        int w = f & 63, oc = f >> 6;
        float s = b1[oc];
        #pragma unroll
        for (int kzi = 0; kzi < KZ; ++kzi) {
            unsigned u = P[(((size_t)(kzi * 4 + b) * 128 + oc) * 64 + h) * 64 + w];
            s += __uint_as_float(u << 16);
        }
        k1s[w * 140 + oc] = s;
    }
    __syncthreads();

    const int w = t & 63, jg = t >> 6;
    float accj[7];
    if (jg < 7) {
        #pragma unroll
        for (int jj = 0; jj < 7; ++jj) accj[jj] = b2[7 * jg + jj];
        const float4* kv = (const float4*)&k1s[w * 140];
        for (int oc4 = 0; oc4 < 32; ++oc4) {
            float4 v = kv[oc4];
            #pragma unroll
            for (int jj = 0; jj < 7; ++jj) {
                const float* wr = w2 + (size_t)(7 * jg + jj) * OC1 + 4 * oc4;
                accj[jj] += v.x * wr[0] + v.y * wr[1] + v.z * wr[2] + v.w * wr[3];
            }
        }
        #pragma unroll
        for (int jj = 0; jj < 7; ++jj) k2s[w * 56 + 7 * jg + jj] = accj[jj];
    } else {
        #pragma unroll
        for (int j = 49; j < 56; ++j) k2s[w * 56 + j] = -1e30f;
    }
    __syncthreads();

    float4 vv[13];
    const float4* k2v = (const float4*)&k2s[w * 56];
    float m = -1e30f;
    #pragma unroll
    for (int i = 0; i < 13; ++i) {
        vv[i] = k2v[i];
        m = fmaxf(m, fmaxf(fmaxf(vv[i].x, vv[i].y), fmaxf(vv[i].z, vv[i].w)));
    }
    float s = 0.f;
    #pragma unroll
    for (int i = 0; i < 13; ++i) {
        s += __expf(vv[i].x - m) + __expf(vv[i].y - m)
           + __expf(vv[i].z - m) + __expf(vv[i].w - m);
    }
    const float inv = 1.f / s;
    if (jg < 7) {
        #pragma unroll
        for (int jj = 0; jj < 7; ++jj)
            A[((size_t)b * NJ + 7 * jg + jj) * 4096 + h * 64 + w] =
                __expf(accj[jj] - m) * inv;
    }
}

// ---------------------------------------------------------------------------
// gather: 49-tap dilated softmax-weighted sum, one 64-channel pass per block.
// grid (64 h, 4 b, 4 pass) = 1024 blocks; block 512; LDS 12.5 KB -> high TLP.
// ---------------------------------------------------------------------------
__global__ __launch_bounds__(512) void gather_kernel(
    const float* __restrict__ A, const float* __restrict__ x,
    float* __restrict__ out)
{
    __shared__ float as[NJ * 64];     // 12,544 B
    const int h = blockIdx.x, b = blockIdx.y, pass = blockIdx.z;
    const int t = threadIdx.x;

    for (int f = t; f < NJ * 64; f += 512)
        as[f] = A[((size_t)b * NJ + (f >> 6)) * 4096 + h * 64 + (f & 63)];
    __syncthreads();

    // thread = (wp 16) x (cs 32); this block covers channels pass*64..+63.
    const int wp = t & 15, cs = t >> 4;
    const int w0 = wp * 4;
    float* outb = out + (size_t)b * CIN * 4096 + (size_t)h * 64 + w0;

    const int c0 = pass * 64 + cs * 2;
    const float* xb = x + (size_t)(b * CIN + c0) * 4096;
    float ac[2][4];
    #pragma unroll
    for (int c = 0; c < 2; ++c)
        #pragma unroll
        for (int wi = 0; wi < 4; ++wi) ac[c][wi] = 0.f;

    #pragma unroll
    for (int u = 0; u < 7; ++u) {
        const int row = h + 2 * u - 6;
        if ((unsigned)row >= 64u) continue;
        float xr[2][20];
        #pragma unroll
        for (int c = 0; c < 2; ++c) {
            const float4* rp = (const float4*)(xb + (size_t)c * 4096 + row * 64);
            #pragma unroll
            for (int j = 0; j < 5; ++j) {
                const int i4 = wp - 2 + j;
                float4 g = make_float4(0.f, 0.f, 0.f, 0.f);
                if ((unsigned)i4 < 16u) g = rp[i4];
                xr[c][4 * j + 0] = g.x; xr[c][4 * j + 1] = g.y;
                xr[c][4 * j + 2] = g.z; xr[c][4 * j + 3] = g.w;
            }
        }
        #pragma unroll
        for (int v = 0; v < 7; ++v) {
            const float4 a4 = *(const float4*)&as[(u * 7 + v) * 64 + w0];
            const float av[4] = {a4.x, a4.y, a4.z, a4.w};
            #pragma unroll
            for (int wi = 0; wi < 4; ++wi)
                #pragma unroll
                for (int c = 0; c < 2; ++c)
                    ac[c][wi] += av[wi] * xr[c][wi + 2 * v + 2];
        }
    }
    #pragma unroll
    for (int c = 0; c < 2; ++c) {
        float4 st = make_float4(ac[c][0], ac[c][1], ac[c][2], ac[c][3]);
        *(float4*)&outb[(size_t)(c0 + c) * 4096] = st;
    }
}

// ---------------------------------------------------------------------------
// ws layout:
//   w1t bf16 [8][49][128][32]            3,211,264 B   (dead after conv1)
//   A   f32  [4][49][64][64]             3,211,264 B   -- ALIASED onto w1t
//   xbf bf16 [4][76][80][256]           12,451,840 B
//   P   bf16 [8][4][128][4096]          33,554,432 B   (total ~49.2 MB)
// ---------------------------------------------------------------------------
extern "C" void kernel_launch(void* const* d_in, const int* in_sizes, int n_in,
                              void* d_out, int out_size, void* d_ws, size_t ws_size,
                              hipStream_t stream) {
    const float* x  = (const float*)d_in[0];
    const float* w1 = (const float*)d_in[1];
    const float* b1 = (const float*)d_in[2];
    const float* w2 = (const float*)d_in[3];
    const float* b2 = (const float*)d_in[4];
    float* out = (float*)d_out;

    unsigned short* w1t = (unsigned short*)d_ws;
    float*          Abuf = (float*)d_ws;                 // alias: w1t dead by then
    unsigned short* xbf = (unsigned short*)((char*)d_ws + 3211264);
    unsigned short* P   = (unsigned short*)((char*)d_ws + 3211264 + 12451840);

    wtrans_kernel<<<256, 256, 0, stream>>>(w1, w1t);
    xtrans_kernel<<<dim3(76, 4, 2), 256, 0, stream>>>(x, xbf);
    conv1_mfma_kernel<<<dim3(32, KZ, 4), 256, 0, stream>>>(xbf, w1t, P);
    attn_kernel<<<dim3(HW, 4), 512, 0, stream>>>(P, w2, b2, b1, Abuf);
    gather_kernel<<<dim3(HW, 4, 4), 512, 0, stream>>>(Abuf, x, out);
}